// Round 13
// baseline (876.457 us; speedup 1.0000x reference)
//
#include <hip/hip_runtime.h>
#include <hip/hip_bf16.h>

#define NN 50000
#define EE 800000
#define DD 128
#define RCHUNK 32

typedef __attribute__((ext_vector_type(8))) short short8;
typedef __attribute__((ext_vector_type(4))) float floatx4;

__device__ __forceinline__ unsigned short f2bf(float f) {   // RNE
    unsigned int x = __float_as_uint(f);
    unsigned int r = x + 0x7fffu + ((x >> 16) & 1u);
    return (unsigned short)(r >> 16);
}
__device__ __forceinline__ float2 bf2x2(unsigned int u) {   // [lo,hi] bf16 pair
    return make_float2(__uint_as_float(u << 16), __uint_as_float(u & 0xffff0000u));
}

// ---------------- degree (guarded) ----------------
__global__ void k_deg(const int* __restrict__ ei, int* __restrict__ deg) {
    int e = blockIdx.x * 256 + threadIdx.x;
    if (e < EE) {
        int d = ei[EE + e];
        if (d >= 0 && d < NN) atomicAdd(&deg[d], 1);
    }
}

// ---------------- CSR scan stage 1 ----------------
__global__ void k_scan_block(const int* __restrict__ deg, int* __restrict__ scanned,
                             int* __restrict__ blocksum) {
    __shared__ int lds[256];
    int t = threadIdx.x;
    int i = blockIdx.x * 256 + t;
    int v = (i < NN) ? deg[i] : 0;
    lds[t] = v;
    __syncthreads();
    for (int off = 1; off < 256; off <<= 1) {
        int add = (t >= off) ? lds[t - off] : 0;
        __syncthreads();
        lds[t] += add;
        __syncthreads();
    }
    if (i < NN) scanned[i] = lds[t];
    if (t == 255) blocksum[blockIdx.x] = lds[255];
}

// ---------------- CSR scan stage 2 (top-scan + final + dis) ----------------
__global__ void k_scan_final(const int* __restrict__ deg, const int* __restrict__ scanned,
                             const int* __restrict__ blocksum, int nb,
                             int* __restrict__ rowptr, int* __restrict__ cursor,
                             float* __restrict__ dis) {
    __shared__ int lds[256];
    int t = threadIdx.x;
    int v = (t < nb) ? blocksum[t] : 0;
    lds[t] = v;
    __syncthreads();
    for (int off = 1; off < 256; off <<= 1) {
        int add = (t >= off) ? lds[t - off] : 0;
        __syncthreads();
        lds[t] += add;
        __syncthreads();
    }
    int boff = (blockIdx.x == 0) ? 0 : lds[blockIdx.x - 1];
    if (blockIdx.x == 0 && t == 0) rowptr[NN] = lds[nb - 1];
    int i = blockIdx.x * 256 + t;
    if (i < NN) {
        int rv = scanned[i] - deg[i] + boff;
        rowptr[i] = rv;
        cursor[i] = rv;
        dis[i] = rsqrtf((float)deg[i] + 1.0f);
    }
}

__global__ void k_fill(const int* __restrict__ ei, int* __restrict__ cursor,
                       int* __restrict__ csr) {
    int e = blockIdx.x * 256 + threadIdx.x;
    if (e < EE) {
        int s = ei[e];
        int d = ei[EE + e];
        if ((unsigned)s < (unsigned)NN && (unsigned)d < (unsigned)NN) {
            int pos = atomicAdd(&cursor[d], 1);
            csr[pos] = s;
        }
    }
}

// ---------------- W prep: fp32 [k][c] -> bf16 FRAGMENT ORDER, all 5 mats ----
__global__ void k_wprep(const float* __restrict__ conv_w, const float* __restrict__ mlp_w,
                        unsigned short* __restrict__ Wf) {
    int g = blockIdx.x * 256 + threadIdx.x;        // [0, 81920)
    int m = g >> 14;
    int idx = g & 16383;
    int j  = idx & 7;
    int n  = (idx >> 3) & 15;
    int q  = (idx >> 7) & 3;
    int kk = (idx >> 9) & 3;
    int nt = (idx >> 11) & 1;
    int w  = (idx >> 12) & 3;
    int k = kk * 32 + q * 8 + j;
    int c = w * 32 + nt * 16 + n;
    const float* src = (m < 3) ? (conv_w + m * 16384) : (mlp_w + (m - 3) * 16384);
    Wf[g] = f2bf(src[k * 128 + c]);
}

// ---------------- conv MFMA GEMM: HS = pro(IN) @ W * dis -> bf16 ----------------
#define LSTR 136
template<int PRO>
__global__ __launch_bounds__(256) void k_gemm_conv(const float* __restrict__ IN,
                                                   const unsigned short* __restrict__ Wf,
                                                   const float* __restrict__ dis,
                                                   const float* __restrict__ cs,
                                                   const float* __restrict__ css,
                                                   const float* __restrict__ gamma,
                                                   const float* __restrict__ beta,
                                                   unsigned short* __restrict__ OUT) {
    __shared__ unsigned short Al[64 * LSTR];
    __shared__ float bnscL[128], bnshL[128];
    const int tid = threadIdx.x;
    const int lane = tid & 63;
    const int w = tid >> 6;
    const int row0 = blockIdx.x * 64;

    if (PRO) {
        if (tid < 128) {
            const float invn = 1.f / (float)NN;
            float mean = cs[tid] * invn;
            float var = css[tid] * invn - mean * mean;
            float sc = gamma[tid] * rsqrtf(fmaxf(var, 0.f) + 1e-5f);
            bnscL[tid] = sc;
            bnshL[tid] = beta[tid] - mean * sc;
        }
        __syncthreads();
    }

    short8 bf[2][4];
    {
        const uint4* Wq = (const uint4*)Wf;
#pragma unroll
        for (int nt = 0; nt < 2; ++nt)
#pragma unroll
            for (int kk = 0; kk < 4; ++kk) {
                uint4 u = Wq[((w * 2 + nt) * 4 + kk) * 64 + lane];
                bf[nt][kk] = *(short8*)&u;
            }
    }

    {
        int r = tid >> 2, kq = (tid & 3) * 32;
        int gr = row0 + r;
        unsigned short tmp[32];
#pragma unroll
        for (int i = 0; i < 8; ++i) {
            float4 v = make_float4(0.f, 0.f, 0.f, 0.f);
            if (gr < NN) v = *(const float4*)&IN[(size_t)gr * DD + kq + i * 4];
            if (PRO) {
                float4 sc = *(const float4*)&bnscL[kq + i * 4];
                float4 sh = *(const float4*)&bnshL[kq + i * 4];
                v.x = fmaf(v.x, sc.x, sh.x);
                v.y = fmaf(v.y, sc.y, sh.y);
                v.z = fmaf(v.z, sc.z, sh.z);
                v.w = fmaf(v.w, sc.w, sh.w);
                v.x = fmaxf(v.x, 0.f); v.y = fmaxf(v.y, 0.f);
                v.z = fmaxf(v.z, 0.f); v.w = fmaxf(v.w, 0.f);
            }
            tmp[i * 4 + 0] = f2bf(v.x); tmp[i * 4 + 1] = f2bf(v.y);
            tmp[i * 4 + 2] = f2bf(v.z); tmp[i * 4 + 3] = f2bf(v.w);
        }
#pragma unroll
        for (int j = 0; j < 4; ++j)
            *(uint4*)&Al[r * LSTR + kq + j * 8] = ((uint4*)tmp)[j];
    }
    __syncthreads();

    const int n = lane & 15, q = lane >> 4;
    floatx4 acc[4][2];
#pragma unroll
    for (int mt = 0; mt < 4; ++mt)
#pragma unroll
        for (int nt = 0; nt < 2; ++nt)
            acc[mt][nt] = (floatx4){0.f, 0.f, 0.f, 0.f};

#pragma unroll
    for (int kk = 0; kk < 4; ++kk) {
        int ko = kk * 32 + q * 8;
#pragma unroll
        for (int mt = 0; mt < 4; ++mt) {
            short8 a = *(const short8*)&Al[(mt * 16 + n) * LSTR + ko];
            acc[mt][0] = __builtin_amdgcn_mfma_f32_16x16x32_bf16(a, bf[0][kk], acc[mt][0], 0, 0, 0);
            acc[mt][1] = __builtin_amdgcn_mfma_f32_16x16x32_bf16(a, bf[1][kk], acc[mt][1], 0, 0, 0);
        }
    }

#pragma unroll
    for (int mt = 0; mt < 4; ++mt) {
#pragma unroll
        for (int reg = 0; reg < 4; ++reg) {
            int r = row0 + mt * 16 + q * 4 + reg;
            if (r < NN) {
                float sc = dis[r];
                OUT[(size_t)r * DD + w * 32 + n]      = f2bf(acc[mt][0][reg] * sc);
                OUT[(size_t)r * DD + w * 32 + 16 + n] = f2bf(acc[mt][1][reg] * sc);
            }
        }
    }
}

// ---------------- fused MLP + head ----------------
__global__ __launch_bounds__(256) void k_mlp_head(const float* __restrict__ IN,
                                                  const unsigned short* __restrict__ Wf4,
                                                  const unsigned short* __restrict__ Wf5,
                                                  const float* __restrict__ b4,
                                                  const float* __restrict__ b5,
                                                  const float* __restrict__ cs,
                                                  const float* __restrict__ css,
                                                  const float* __restrict__ gamma,
                                                  const float* __restrict__ beta,
                                                  const float* __restrict__ ow,
                                                  const float* __restrict__ ob,
                                                  float* __restrict__ out) {
    __shared__ unsigned short Al[64 * LSTR];
    __shared__ float bnscL[128], bnshL[128];
    __shared__ float redH[4][64];
    const int tid = threadIdx.x;
    const int lane = tid & 63;
    const int w = tid >> 6;
    const int row0 = blockIdx.x * 64;
    const int n = lane & 15, q = lane >> 4;

    if (tid < 128) {
        const float invn = 1.f / (float)NN;
        float mean = cs[tid] * invn;
        float var = css[tid] * invn - mean * mean;
        float sc = gamma[tid] * rsqrtf(fmaxf(var, 0.f) + 1e-5f);
        bnscL[tid] = sc;
        bnshL[tid] = beta[tid] - mean * sc;
    }
    __syncthreads();

    {
        int r = tid >> 2, kq = (tid & 3) * 32;
        int gr = row0 + r;
        unsigned short tmp[32];
#pragma unroll
        for (int i = 0; i < 8; ++i) {
            float4 v = make_float4(0.f, 0.f, 0.f, 0.f);
            if (gr < NN) v = *(const float4*)&IN[(size_t)gr * DD + kq + i * 4];
            float4 sc = *(const float4*)&bnscL[kq + i * 4];
            float4 sh = *(const float4*)&bnshL[kq + i * 4];
            v.x = fmaf(v.x, sc.x, sh.x);
            v.y = fmaf(v.y, sc.y, sh.y);
            v.z = fmaf(v.z, sc.z, sh.z);
            v.w = fmaf(v.w, sc.w, sh.w);
            tmp[i * 4 + 0] = f2bf(v.x); tmp[i * 4 + 1] = f2bf(v.y);
            tmp[i * 4 + 2] = f2bf(v.z); tmp[i * 4 + 3] = f2bf(v.w);
        }
#pragma unroll
        for (int j = 0; j < 4; ++j)
            *(uint4*)&Al[r * LSTR + kq + j * 8] = ((uint4*)tmp)[j];
    }
    __syncthreads();

    floatx4 acc[4][2];
#pragma unroll
    for (int mt = 0; mt < 4; ++mt)
#pragma unroll
        for (int nt = 0; nt < 2; ++nt)
            acc[mt][nt] = (floatx4){0.f, 0.f, 0.f, 0.f};
    {
        const uint4* Wq = (const uint4*)Wf4;
#pragma unroll
        for (int kk = 0; kk < 4; ++kk) {
            uint4 u0 = Wq[((w * 2 + 0) * 4 + kk) * 64 + lane];
            uint4 u1 = Wq[((w * 2 + 1) * 4 + kk) * 64 + lane];
            int ko = kk * 32 + q * 8;
#pragma unroll
            for (int mt = 0; mt < 4; ++mt) {
                short8 a = *(const short8*)&Al[(mt * 16 + n) * LSTR + ko];
                acc[mt][0] = __builtin_amdgcn_mfma_f32_16x16x32_bf16(a, *(short8*)&u0, acc[mt][0], 0, 0, 0);
                acc[mt][1] = __builtin_amdgcn_mfma_f32_16x16x32_bf16(a, *(short8*)&u1, acc[mt][1], 0, 0, 0);
            }
        }
    }
    __syncthreads();

    {
        float b0c = b4[w * 32 + n], b1c = b4[w * 32 + 16 + n];
#pragma unroll
        for (int mt = 0; mt < 4; ++mt) {
#pragma unroll
            for (int reg = 0; reg < 4; ++reg) {
                int r = mt * 16 + q * 4 + reg;
                Al[r * LSTR + w * 32 + n]      = f2bf(fmaxf(acc[mt][0][reg] + b0c, 0.f));
                Al[r * LSTR + w * 32 + 16 + n] = f2bf(fmaxf(acc[mt][1][reg] + b1c, 0.f));
            }
        }
    }
    __syncthreads();

#pragma unroll
    for (int mt = 0; mt < 4; ++mt)
#pragma unroll
        for (int nt = 0; nt < 2; ++nt)
            acc[mt][nt] = (floatx4){0.f, 0.f, 0.f, 0.f};
    {
        const uint4* Wq = (const uint4*)Wf5;
#pragma unroll
        for (int kk = 0; kk < 4; ++kk) {
            uint4 u0 = Wq[((w * 2 + 0) * 4 + kk) * 64 + lane];
            uint4 u1 = Wq[((w * 2 + 1) * 4 + kk) * 64 + lane];
            int ko = kk * 32 + q * 8;
#pragma unroll
            for (int mt = 0; mt < 4; ++mt) {
                short8 a = *(const short8*)&Al[(mt * 16 + n) * LSTR + ko];
                acc[mt][0] = __builtin_amdgcn_mfma_f32_16x16x32_bf16(a, *(short8*)&u0, acc[mt][0], 0, 0, 0);
                acc[mt][1] = __builtin_amdgcn_mfma_f32_16x16x32_bf16(a, *(short8*)&u1, acc[mt][1], 0, 0, 0);
            }
        }
    }
    {
        float b0c = b5[w * 32 + n], b1c = b5[w * 32 + 16 + n];
        float w0c = ow[w * 32 + n], w1c = ow[w * 32 + 16 + n];
#pragma unroll
        for (int mt = 0; mt < 4; ++mt) {
#pragma unroll
            for (int reg = 0; reg < 4; ++reg) {
                float h0 = fmaxf(acc[mt][0][reg] + b0c, 0.f);
                float h1 = fmaxf(acc[mt][1][reg] + b1c, 0.f);
                float p = fmaf(h0, w0c, h1 * w1c);
                p += __shfl_xor(p, 1);
                p += __shfl_xor(p, 2);
                p += __shfl_xor(p, 4);
                p += __shfl_xor(p, 8);
                if (n == 0) redH[w][mt * 16 + q * 4 + reg] = p;
            }
        }
        __syncthreads();
        if (tid < 64) {
            int r = row0 + tid;
            if (r < NN) {
                float z = (redH[0][tid] + redH[1][tid]) + (redH[2][tid] + redH[3][tid]) + ob[0];
                out[r] = 1.f / (1.f + expf(-z));
            }
        }
    }
}
#undef LSTR

// ---------------- XCD-sliced gather: 4 column slices of 32 cols (3.2MB, L2-fit) --
// slice preference = actual XCC_ID (work-stealing guarantees completion even if
// the id were wrong). Wave: jj=lane>>4 neighbor slot x c=lane&15 -> 2 cols (4B).
template<int RELU>
__global__ __launch_bounds__(256) void k_gather(const int* __restrict__ rowptr,
                                                const int* __restrict__ csr,
                                                const unsigned int* __restrict__ HSu, // 64 uints/row
                                                const float* __restrict__ dis,
                                                const float* __restrict__ bias,
                                                float* __restrict__ OUT,
                                                float* __restrict__ colsum,
                                                float* __restrict__ colsumsq,
                                                int* __restrict__ wctr) {
    const int tid = threadIdx.x;
    const int lane = tid & 63;
    const int wid = tid >> 6;
    const int c = lane & 15;           // uint index (2 cols) within 64B slice-row
    const int jj = lane >> 4;
    int xcc;
    asm("s_getreg_b32 %0, hwreg(HW_REG_XCC_ID)" : "=s"(xcc));
    __shared__ int chunkS;

    for (int sp = 0; sp < 4; ++sp) {
        const int s = (xcc + sp) & 3;
        const unsigned int* HSs = HSu + s * 16;
        float2 b = ((const float2*)bias)[s * 16 + c];
        float sum0 = 0.f, sq0 = 0.f, sum1 = 0.f, sq1 = 0.f;
        bool did = false;
        for (;;) {
            __syncthreads();
            if (tid == 0) chunkS = atomicAdd(&wctr[s], RCHUNK);
            __syncthreads();
            int chunk = chunkS;
            if (chunk >= NN) break;
            did = true;
            int r0 = chunk + wid * (RCHUNK / 4);
            int r1 = min(r0 + RCHUNK / 4, NN);
            for (int r = r0; r < r1; ++r) {
                int beg = rowptr[r], end = rowptr[r + 1];
                float a0 = 0.f, a1 = 0.f;
                if (jj == 0) {
                    float2 p = bf2x2(HSs[(size_t)r * 64 + c]);
                    a0 += p.x; a1 += p.y;
                }
                int e1 = end - 1;
                for (int j = beg; j < end; j += 16) {
                    int i0 = j + jj, i1 = j + 4 + jj, i2 = j + 8 + jj, i3 = j + 12 + jj;
                    int s0 = csr[min(i0, e1)];
                    int s1 = csr[min(i1, e1)];
                    int s2 = csr[min(i2, e1)];
                    int s3 = csr[min(i3, e1)];
                    unsigned u0 = HSs[(size_t)s0 * 64 + c];
                    unsigned u1 = HSs[(size_t)s1 * 64 + c];
                    unsigned u2 = HSs[(size_t)s2 * 64 + c];
                    unsigned u3 = HSs[(size_t)s3 * 64 + c];
                    if (i0 < end) { float2 p = bf2x2(u0); a0 += p.x; a1 += p.y; }
                    if (i1 < end) { float2 p = bf2x2(u1); a0 += p.x; a1 += p.y; }
                    if (i2 < end) { float2 p = bf2x2(u2); a0 += p.x; a1 += p.y; }
                    if (i3 < end) { float2 p = bf2x2(u3); a0 += p.x; a1 += p.y; }
                }
                a0 += __shfl_xor(a0, 16); a0 += __shfl_xor(a0, 32);
                a1 += __shfl_xor(a1, 16); a1 += __shfl_xor(a1, 32);
                if (jj == 0) {
                    float dr = dis[r];
                    float v0 = fmaf(dr, a0, b.x);
                    float v1 = fmaf(dr, a1, b.y);
                    if (RELU) { v0 = fmaxf(v0, 0.f); v1 = fmaxf(v1, 0.f); }
                    float* op = OUT + (size_t)r * DD + s * 32 + c * 2;
                    __builtin_nontemporal_store(v0, op);
                    __builtin_nontemporal_store(v1, op + 1);
                    sum0 += v0; sq0 += v0 * v0;
                    sum1 += v1; sq1 += v1 * v1;
                }
            }
        }
        if (did && jj == 0) {
            atomicAdd(&colsum[s * 32 + c * 2],       sum0);
            atomicAdd(&colsum[s * 32 + c * 2 + 1],   sum1);
            atomicAdd(&colsumsq[s * 32 + c * 2],     sq0);
            atomicAdd(&colsumsq[s * 32 + c * 2 + 1], sq1);
        }
    }
}

extern "C" void kernel_launch(void* const* d_in, const int* in_sizes, int n_in,
                              void* d_out, int out_size, void* d_ws, size_t ws_size,
                              hipStream_t stream) {
    const float* x      = (const float*)d_in[0];
    const int*   ei     = (const int*)d_in[1];
    const float* conv_w = (const float*)d_in[2];
    const float* conv_b = (const float*)d_in[3];
    const float* bn_g   = (const float*)d_in[4];
    const float* bn_b   = (const float*)d_in[5];
    const float* mlp_w  = (const float*)d_in[6];
    const float* mlp_b  = (const float*)d_in[7];
    const float* out_w  = (const float*)d_in[8];
    const float* out_b  = (const float*)d_in[9];
    float* out = (float*)d_out;

    const size_t ND4 = (size_t)NN * DD * 4;   // 25,600,000 B
    char* ws = (char*)d_ws;
    size_t off = 0;
    float* B0      = (float*)(ws + off); off += ND4;            // fp32 features
    unsigned short* B1b = (unsigned short*)(ws + off); off += ND4 / 2;  // bf16 HS
    int*   deg     = (int*)  (ws + off); off += 204800;         // zeroed region start
    float* cs3     = (float*)(ws + off); off += 3 * 512;
    float* css3    = (float*)(ws + off); off += 3 * 512;
    int*   wctr    = (int*)  (ws + off); off += 64;             // 3 layers x 4 slices (zeroed end)
    float* dis     = (float*)(ws + off); off += 204800;
    int*   rowptr  = (int*)  (ws + off); off += 204804 + 60;
    int*   cursor  = (int*)  (ws + off); off += 204800;
    int*   bsum    = (int*)  (ws + off); off += 1024;
    unsigned short* Wfb = (unsigned short*)(ws + off); off += 5 * 16384 * 2;
    int*   csr     = (int*)  (ws + off); off += (size_t)EE * 4;

    const int gemm_grid = (NN + 63) / 64;     // 782
    const int nscan = (NN + 255) / 256;       // 196
    const int gather_grid = 2048;

    hipMemsetAsync(deg, 0, 204800 + 6 * 512 + 64, stream);

    k_deg<<<(EE + 255) / 256, 256, 0, stream>>>(ei, deg);
    k_scan_block<<<nscan, 256, 0, stream>>>(deg, cursor, bsum);
    k_scan_final<<<nscan, 256, 0, stream>>>(deg, cursor, bsum, nscan, rowptr, cursor, dis);
    k_fill<<<(EE + 255) / 256, 256, 0, stream>>>(ei, cursor, csr);
    k_wprep<<<320, 256, 0, stream>>>(conv_w, mlp_w, Wfb);

    // ---- layer 0 ----
    k_gemm_conv<0><<<gemm_grid, 256, 0, stream>>>(x, Wfb, dis,
        nullptr, nullptr, nullptr, nullptr, B1b);
    k_gather<0><<<gather_grid, 256, 0, stream>>>(rowptr, csr, (const unsigned int*)B1b, dis, conv_b, B0, cs3, css3, wctr);

    // ---- layer 1 ----
    k_gemm_conv<1><<<gemm_grid, 256, 0, stream>>>(B0, Wfb + 16384, dis,
        cs3, css3, bn_g, bn_b, B1b);
    k_gather<0><<<gather_grid, 256, 0, stream>>>(rowptr, csr, (const unsigned int*)B1b, dis, conv_b + DD, B0, cs3 + 128, css3 + 128, wctr + 4);

    // ---- layer 2 ----
    k_gemm_conv<1><<<gemm_grid, 256, 0, stream>>>(B0, Wfb + 2 * 16384, dis,
        cs3 + 128, css3 + 128, bn_g + DD, bn_b + DD, B1b);
    k_gather<1><<<gather_grid, 256, 0, stream>>>(rowptr, csr, (const unsigned int*)B1b, dis, conv_b + 2 * DD, B0, cs3 + 256, css3 + 256, wctr + 8);

    // ---- fused MLP + head ----
    k_mlp_head<<<gemm_grid, 256, 0, stream>>>(B0, Wfb + 3 * 16384, Wfb + 4 * 16384,
        mlp_b, mlp_b + DD, cs3 + 256, css3 + 256, bn_g + DD, bn_b + DD, out_w, out_b, out);
}

// Round 14
// 456.539 us; speedup vs baseline: 1.9198x; 1.9198x over previous
//
#include <hip/hip_runtime.h>
#include <hip/hip_bf16.h>

#define NN 50000
#define EE 800000
#define DD 128

typedef __attribute__((ext_vector_type(8))) short short8;
typedef __attribute__((ext_vector_type(4))) float floatx4;

__device__ __forceinline__ unsigned short f2bf(float f) {   // RNE
    unsigned int x = __float_as_uint(f);
    unsigned int r = x + 0x7fffu + ((x >> 16) & 1u);
    return (unsigned short)(r >> 16);
}
__device__ __forceinline__ float2 bf2x2(unsigned int u) {   // [lo,hi] bf16 pair
    return make_float2(__uint_as_float(u << 16), __uint_as_float(u & 0xffff0000u));
}

// ---------------- degree (guarded) ----------------
__global__ void k_deg(const int* __restrict__ ei, int* __restrict__ deg) {
    int e = blockIdx.x * 256 + threadIdx.x;
    if (e < EE) {
        int d = ei[EE + e];
        if (d >= 0 && d < NN) atomicAdd(&deg[d], 1);
    }
}

// ---------------- CSR scan stage 1 ----------------
__global__ void k_scan_block(const int* __restrict__ deg, int* __restrict__ scanned,
                             int* __restrict__ blocksum) {
    __shared__ int lds[256];
    int t = threadIdx.x;
    int i = blockIdx.x * 256 + t;
    int v = (i < NN) ? deg[i] : 0;
    lds[t] = v;
    __syncthreads();
    for (int off = 1; off < 256; off <<= 1) {
        int add = (t >= off) ? lds[t - off] : 0;
        __syncthreads();
        lds[t] += add;
        __syncthreads();
    }
    if (i < NN) scanned[i] = lds[t];
    if (t == 255) blocksum[blockIdx.x] = lds[255];
}

// ---------------- CSR scan stage 2 (top-scan + final + dis) ----------------
__global__ void k_scan_final(const int* __restrict__ deg, const int* __restrict__ scanned,
                             const int* __restrict__ blocksum, int nb,
                             int* __restrict__ rowptr, int* __restrict__ cursor,
                             float* __restrict__ dis) {
    __shared__ int lds[256];
    int t = threadIdx.x;
    int v = (t < nb) ? blocksum[t] : 0;
    lds[t] = v;
    __syncthreads();
    for (int off = 1; off < 256; off <<= 1) {
        int add = (t >= off) ? lds[t - off] : 0;
        __syncthreads();
        lds[t] += add;
        __syncthreads();
    }
    int boff = (blockIdx.x == 0) ? 0 : lds[blockIdx.x - 1];
    if (blockIdx.x == 0 && t == 0) rowptr[NN] = lds[nb - 1];
    int i = blockIdx.x * 256 + t;
    if (i < NN) {
        int rv = scanned[i] - deg[i] + boff;
        rowptr[i] = rv;
        cursor[i] = rv;
        dis[i] = rsqrtf((float)deg[i] + 1.0f);
    }
}

__global__ void k_fill(const int* __restrict__ ei, int* __restrict__ cursor,
                       int* __restrict__ csr) {
    int e = blockIdx.x * 256 + threadIdx.x;
    if (e < EE) {
        int s = ei[e];
        int d = ei[EE + e];
        if ((unsigned)s < (unsigned)NN && (unsigned)d < (unsigned)NN) {
            int pos = atomicAdd(&cursor[d], 1);
            csr[pos] = s;
        }
    }
}

// ---------------- ELL build: width 32, pad with NN (zero HS row) ----------------
__global__ void k_ell(const int* __restrict__ rowptr, const int* __restrict__ csr,
                      int* __restrict__ ell) {
    int t = blockIdx.x * 256 + threadIdx.x;     // [0, NN*32)
    if (t >= NN * 32) return;
    int r = t >> 5, slot = t & 31;
    int beg = rowptr[r];
    int d = rowptr[r + 1] - beg;
    ell[t] = (slot < d) ? csr[beg + slot] : NN;
}

// ---------------- W prep (fragment order) + zero HS pad row ----------------
__global__ void k_wprep(const float* __restrict__ conv_w, const float* __restrict__ mlp_w,
                        unsigned short* __restrict__ Wf, unsigned int* __restrict__ hsrow) {
    int g = blockIdx.x * 256 + threadIdx.x;
    if (g < 81920) {
        int m = g >> 14;
        int idx = g & 16383;
        int j  = idx & 7;
        int n  = (idx >> 3) & 15;
        int q  = (idx >> 7) & 3;
        int kk = (idx >> 9) & 3;
        int nt = (idx >> 11) & 1;
        int w  = (idx >> 12) & 3;
        int k = kk * 32 + q * 8 + j;
        int c = w * 32 + nt * 16 + n;
        const float* src = (m < 3) ? (conv_w + m * 16384) : (mlp_w + (m - 3) * 16384);
        Wf[g] = f2bf(src[k * 128 + c]);
    } else if (g - 81920 < 64) {
        hsrow[g - 81920] = 0u;                  // zero pad row HS[NN]
    }
}

// ---------------- conv MFMA GEMM: HS = pro(IN) @ W * dis -> bf16 ----------------
#define LSTR 136
template<int PRO>
__global__ __launch_bounds__(256) void k_gemm_conv(const float* __restrict__ IN,
                                                   const unsigned short* __restrict__ Wf,
                                                   const float* __restrict__ dis,
                                                   const float* __restrict__ cs,
                                                   const float* __restrict__ css,
                                                   const float* __restrict__ gamma,
                                                   const float* __restrict__ beta,
                                                   unsigned short* __restrict__ OUT) {
    __shared__ unsigned short Al[64 * LSTR];
    __shared__ float bnscL[128], bnshL[128];
    const int tid = threadIdx.x;
    const int lane = tid & 63;
    const int w = tid >> 6;
    const int row0 = blockIdx.x * 64;

    if (PRO) {
        if (tid < 128) {
            const float invn = 1.f / (float)NN;
            float mean = cs[tid] * invn;
            float var = css[tid] * invn - mean * mean;
            float sc = gamma[tid] * rsqrtf(fmaxf(var, 0.f) + 1e-5f);
            bnscL[tid] = sc;
            bnshL[tid] = beta[tid] - mean * sc;
        }
        __syncthreads();
    }

    short8 bf[2][4];
    {
        const uint4* Wq = (const uint4*)Wf;
#pragma unroll
        for (int nt = 0; nt < 2; ++nt)
#pragma unroll
            for (int kk = 0; kk < 4; ++kk) {
                uint4 u = Wq[((w * 2 + nt) * 4 + kk) * 64 + lane];
                bf[nt][kk] = *(short8*)&u;
            }
    }

    {
        int r = tid >> 2, kq = (tid & 3) * 32;
        int gr = row0 + r;
        unsigned short tmp[32];
#pragma unroll
        for (int i = 0; i < 8; ++i) {
            float4 v = make_float4(0.f, 0.f, 0.f, 0.f);
            if (gr < NN) v = *(const float4*)&IN[(size_t)gr * DD + kq + i * 4];
            if (PRO) {
                float4 sc = *(const float4*)&bnscL[kq + i * 4];
                float4 sh = *(const float4*)&bnshL[kq + i * 4];
                v.x = fmaf(v.x, sc.x, sh.x);
                v.y = fmaf(v.y, sc.y, sh.y);
                v.z = fmaf(v.z, sc.z, sh.z);
                v.w = fmaf(v.w, sc.w, sh.w);
                v.x = fmaxf(v.x, 0.f); v.y = fmaxf(v.y, 0.f);
                v.z = fmaxf(v.z, 0.f); v.w = fmaxf(v.w, 0.f);
            }
            tmp[i * 4 + 0] = f2bf(v.x); tmp[i * 4 + 1] = f2bf(v.y);
            tmp[i * 4 + 2] = f2bf(v.z); tmp[i * 4 + 3] = f2bf(v.w);
        }
#pragma unroll
        for (int j = 0; j < 4; ++j)
            *(uint4*)&Al[r * LSTR + kq + j * 8] = ((uint4*)tmp)[j];
    }
    __syncthreads();

    const int n = lane & 15, q = lane >> 4;
    floatx4 acc[4][2];
#pragma unroll
    for (int mt = 0; mt < 4; ++mt)
#pragma unroll
        for (int nt = 0; nt < 2; ++nt)
            acc[mt][nt] = (floatx4){0.f, 0.f, 0.f, 0.f};

#pragma unroll
    for (int kk = 0; kk < 4; ++kk) {
        int ko = kk * 32 + q * 8;
#pragma unroll
        for (int mt = 0; mt < 4; ++mt) {
            short8 a = *(const short8*)&Al[(mt * 16 + n) * LSTR + ko];
            acc[mt][0] = __builtin_amdgcn_mfma_f32_16x16x32_bf16(a, bf[0][kk], acc[mt][0], 0, 0, 0);
            acc[mt][1] = __builtin_amdgcn_mfma_f32_16x16x32_bf16(a, bf[1][kk], acc[mt][1], 0, 0, 0);
        }
    }

#pragma unroll
    for (int mt = 0; mt < 4; ++mt) {
#pragma unroll
        for (int reg = 0; reg < 4; ++reg) {
            int r = row0 + mt * 16 + q * 4 + reg;
            if (r < NN) {
                float sc = dis[r];
                OUT[(size_t)r * DD + w * 32 + n]      = f2bf(acc[mt][0][reg] * sc);
                OUT[(size_t)r * DD + w * 32 + 16 + n] = f2bf(acc[mt][1][reg] * sc);
            }
        }
    }
}

// ---------------- fused MLP + head ----------------
__global__ __launch_bounds__(256) void k_mlp_head(const float* __restrict__ IN,
                                                  const unsigned short* __restrict__ Wf4,
                                                  const unsigned short* __restrict__ Wf5,
                                                  const float* __restrict__ b4,
                                                  const float* __restrict__ b5,
                                                  const float* __restrict__ cs,
                                                  const float* __restrict__ css,
                                                  const float* __restrict__ gamma,
                                                  const float* __restrict__ beta,
                                                  const float* __restrict__ ow,
                                                  const float* __restrict__ ob,
                                                  float* __restrict__ out) {
    __shared__ unsigned short Al[64 * LSTR];
    __shared__ float bnscL[128], bnshL[128];
    __shared__ float redH[4][64];
    const int tid = threadIdx.x;
    const int lane = tid & 63;
    const int w = tid >> 6;
    const int row0 = blockIdx.x * 64;
    const int n = lane & 15, q = lane >> 4;

    if (tid < 128) {
        const float invn = 1.f / (float)NN;
        float mean = cs[tid] * invn;
        float var = css[tid] * invn - mean * mean;
        float sc = gamma[tid] * rsqrtf(fmaxf(var, 0.f) + 1e-5f);
        bnscL[tid] = sc;
        bnshL[tid] = beta[tid] - mean * sc;
    }
    __syncthreads();

    {
        int r = tid >> 2, kq = (tid & 3) * 32;
        int gr = row0 + r;
        unsigned short tmp[32];
#pragma unroll
        for (int i = 0; i < 8; ++i) {
            float4 v = make_float4(0.f, 0.f, 0.f, 0.f);
            if (gr < NN) v = *(const float4*)&IN[(size_t)gr * DD + kq + i * 4];
            float4 sc = *(const float4*)&bnscL[kq + i * 4];
            float4 sh = *(const float4*)&bnshL[kq + i * 4];
            v.x = fmaf(v.x, sc.x, sh.x);
            v.y = fmaf(v.y, sc.y, sh.y);
            v.z = fmaf(v.z, sc.z, sh.z);
            v.w = fmaf(v.w, sc.w, sh.w);
            tmp[i * 4 + 0] = f2bf(v.x); tmp[i * 4 + 1] = f2bf(v.y);
            tmp[i * 4 + 2] = f2bf(v.z); tmp[i * 4 + 3] = f2bf(v.w);
        }
#pragma unroll
        for (int j = 0; j < 4; ++j)
            *(uint4*)&Al[r * LSTR + kq + j * 8] = ((uint4*)tmp)[j];
    }
    __syncthreads();

    floatx4 acc[4][2];
#pragma unroll
    for (int mt = 0; mt < 4; ++mt)
#pragma unroll
        for (int nt = 0; nt < 2; ++nt)
            acc[mt][nt] = (floatx4){0.f, 0.f, 0.f, 0.f};
    {
        const uint4* Wq = (const uint4*)Wf4;
#pragma unroll
        for (int kk = 0; kk < 4; ++kk) {
            uint4 u0 = Wq[((w * 2 + 0) * 4 + kk) * 64 + lane];
            uint4 u1 = Wq[((w * 2 + 1) * 4 + kk) * 64 + lane];
            int ko = kk * 32 + q * 8;
#pragma unroll
            for (int mt = 0; mt < 4; ++mt) {
                short8 a = *(const short8*)&Al[(mt * 16 + n) * LSTR + ko];
                acc[mt][0] = __builtin_amdgcn_mfma_f32_16x16x32_bf16(a, *(short8*)&u0, acc[mt][0], 0, 0, 0);
                acc[mt][1] = __builtin_amdgcn_mfma_f32_16x16x32_bf16(a, *(short8*)&u1, acc[mt][1], 0, 0, 0);
            }
        }
    }
    __syncthreads();

    {
        float b0c = b4[w * 32 + n], b1c = b4[w * 32 + 16 + n];
#pragma unroll
        for (int mt = 0; mt < 4; ++mt) {
#pragma unroll
            for (int reg = 0; reg < 4; ++reg) {
                int r = mt * 16 + q * 4 + reg;
                Al[r * LSTR + w * 32 + n]      = f2bf(fmaxf(acc[mt][0][reg] + b0c, 0.f));
                Al[r * LSTR + w * 32 + 16 + n] = f2bf(fmaxf(acc[mt][1][reg] + b1c, 0.f));
            }
        }
    }
    __syncthreads();

#pragma unroll
    for (int mt = 0; mt < 4; ++mt)
#pragma unroll
        for (int nt = 0; nt < 2; ++nt)
            acc[mt][nt] = (floatx4){0.f, 0.f, 0.f, 0.f};
    {
        const uint4* Wq = (const uint4*)Wf5;
#pragma unroll
        for (int kk = 0; kk < 4; ++kk) {
            uint4 u0 = Wq[((w * 2 + 0) * 4 + kk) * 64 + lane];
            uint4 u1 = Wq[((w * 2 + 1) * 4 + kk) * 64 + lane];
            int ko = kk * 32 + q * 8;
#pragma unroll
            for (int mt = 0; mt < 4; ++mt) {
                short8 a = *(const short8*)&Al[(mt * 16 + n) * LSTR + ko];
                acc[mt][0] = __builtin_amdgcn_mfma_f32_16x16x32_bf16(a, *(short8*)&u0, acc[mt][0], 0, 0, 0);
                acc[mt][1] = __builtin_amdgcn_mfma_f32_16x16x32_bf16(a, *(short8*)&u1, acc[mt][1], 0, 0, 0);
            }
        }
    }
    {
        float b0c = b5[w * 32 + n], b1c = b5[w * 32 + 16 + n];
        float w0c = ow[w * 32 + n], w1c = ow[w * 32 + 16 + n];
#pragma unroll
        for (int mt = 0; mt < 4; ++mt) {
#pragma unroll
            for (int reg = 0; reg < 4; ++reg) {
                float h0 = fmaxf(acc[mt][0][reg] + b0c, 0.f);
                float h1 = fmaxf(acc[mt][1][reg] + b1c, 0.f);
                float p = fmaf(h0, w0c, h1 * w1c);
                p += __shfl_xor(p, 1);
                p += __shfl_xor(p, 2);
                p += __shfl_xor(p, 4);
                p += __shfl_xor(p, 8);
                if (n == 0) redH[w][mt * 16 + q * 4 + reg] = p;
            }
        }
        __syncthreads();
        if (tid < 64) {
            int r = row0 + tid;
            if (r < NN) {
                float z = (redH[0][tid] + redH[1][tid]) + (redH[2][tid] + redH[3][tid]) + ob[0];
                out[r] = 1.f / (1.f + expf(-z));
            }
        }
    }
}
#undef LSTR

// ---------------- gather: ELL branch-free fast path + CSR heavy fallback ----------
// Wave: c=lane&15 -> 16B chunk, jj=lane>>4 -> neighbor slot group.
// deg<=32 rows: fixed 8 HS loads/lane from ell (pads read zero row NN) -> fully
// pipelineable. deg>32 rows (rare): r12's dynamic CSR loop.
template<int RELU>
__global__ __launch_bounds__(256) void k_gather(const int* __restrict__ rowptr,
                                                const int* __restrict__ csr,
                                                const int* __restrict__ ell,
                                                const uint4* __restrict__ HSq,
                                                const float* __restrict__ dis,
                                                const float* __restrict__ bias,
                                                float* __restrict__ OUT,
                                                float* __restrict__ colsum,
                                                float* __restrict__ colsumsq) {
    const int tid = threadIdx.x;
    const int lane = tid & 63;
    const int wid = tid >> 6;
    const int c = lane & 15;
    const int jj = lane >> 4;
    const int gwave = blockIdx.x * 4 + wid;

    float4 bia0 = ((const float4*)bias)[2 * c];
    float4 bia1 = ((const float4*)bias)[2 * c + 1];
    float sum[8], sq[8];
#pragma unroll
    for (int t = 0; t < 8; ++t) { sum[t] = 0.f; sq[t] = 0.f; }

    for (int r = gwave; r < NN; r += 8192) {
        int beg = rowptr[r], end = rowptr[r + 1];
        int d = end - beg;
        float a[8];
#pragma unroll
        for (int t = 0; t < 8; ++t) a[t] = 0.f;

        if (jj == 0) {   // self loop
            uint4 u = HSq[(size_t)r * 16 + c];
            float2 p0 = bf2x2(u.x), p1 = bf2x2(u.y), p2 = bf2x2(u.z), p3 = bf2x2(u.w);
            a[0] += p0.x; a[1] += p0.y; a[2] += p1.x; a[3] += p1.y;
            a[4] += p2.x; a[5] += p2.y; a[6] += p3.x; a[7] += p3.y;
        }

        if (d <= 32) {
            // branch-free: 8 neighbors per lane from ELL (pads -> zero row)
            const int4* e4 = (const int4*)(ell + r * 32);
            int4 ia = e4[jj];
            int4 ib = e4[jj + 4];
            uint4 v0 = HSq[(size_t)ia.x * 16 + c];
            uint4 v1 = HSq[(size_t)ia.y * 16 + c];
            uint4 v2 = HSq[(size_t)ia.z * 16 + c];
            uint4 v3 = HSq[(size_t)ia.w * 16 + c];
            uint4 v4 = HSq[(size_t)ib.x * 16 + c];
            uint4 v5 = HSq[(size_t)ib.y * 16 + c];
            uint4 v6 = HSq[(size_t)ib.z * 16 + c];
            uint4 v7 = HSq[(size_t)ib.w * 16 + c];
            uint4 vs[8] = {v0, v1, v2, v3, v4, v5, v6, v7};
#pragma unroll
            for (int t = 0; t < 8; ++t) {
                float2 p0 = bf2x2(vs[t].x), p1 = bf2x2(vs[t].y);
                float2 p2 = bf2x2(vs[t].z), p3 = bf2x2(vs[t].w);
                a[0] += p0.x; a[1] += p0.y; a[2] += p1.x; a[3] += p1.y;
                a[4] += p2.x; a[5] += p2.y; a[6] += p3.x; a[7] += p3.y;
            }
        } else {
            int e1 = end - 1;
            for (int j = beg; j < end; j += 16) {
                int i0 = j + jj, i1 = j + 4 + jj, i2 = j + 8 + jj, i3 = j + 12 + jj;
                int s0 = csr[min(i0, e1)];
                int s1 = csr[min(i1, e1)];
                int s2 = csr[min(i2, e1)];
                int s3 = csr[min(i3, e1)];
                uint4 v0 = HSq[(size_t)s0 * 16 + c];
                uint4 v1 = HSq[(size_t)s1 * 16 + c];
                uint4 v2 = HSq[(size_t)s2 * 16 + c];
                uint4 v3 = HSq[(size_t)s3 * 16 + c];
                if (i0 < end) {
                    float2 p0 = bf2x2(v0.x), p1 = bf2x2(v0.y), p2 = bf2x2(v0.z), p3 = bf2x2(v0.w);
                    a[0] += p0.x; a[1] += p0.y; a[2] += p1.x; a[3] += p1.y;
                    a[4] += p2.x; a[5] += p2.y; a[6] += p3.x; a[7] += p3.y;
                }
                if (i1 < end) {
                    float2 p0 = bf2x2(v1.x), p1 = bf2x2(v1.y), p2 = bf2x2(v1.z), p3 = bf2x2(v1.w);
                    a[0] += p0.x; a[1] += p0.y; a[2] += p1.x; a[3] += p1.y;
                    a[4] += p2.x; a[5] += p2.y; a[6] += p3.x; a[7] += p3.y;
                }
                if (i2 < end) {
                    float2 p0 = bf2x2(v2.x), p1 = bf2x2(v2.y), p2 = bf2x2(v2.z), p3 = bf2x2(v2.w);
                    a[0] += p0.x; a[1] += p0.y; a[2] += p1.x; a[3] += p1.y;
                    a[4] += p2.x; a[5] += p2.y; a[6] += p3.x; a[7] += p3.y;
                }
                if (i3 < end) {
                    float2 p0 = bf2x2(v3.x), p1 = bf2x2(v3.y), p2 = bf2x2(v3.z), p3 = bf2x2(v3.w);
                    a[0] += p0.x; a[1] += p0.y; a[2] += p1.x; a[3] += p1.y;
                    a[4] += p2.x; a[5] += p2.y; a[6] += p3.x; a[7] += p3.y;
                }
            }
        }

#pragma unroll
        for (int t = 0; t < 8; ++t) {
            a[t] += __shfl_xor(a[t], 16);
            a[t] += __shfl_xor(a[t], 32);
        }

        if (jj == 0) {
            float dr = dis[r];
            float v[8];
            v[0] = fmaf(dr, a[0], bia0.x); v[1] = fmaf(dr, a[1], bia0.y);
            v[2] = fmaf(dr, a[2], bia0.z); v[3] = fmaf(dr, a[3], bia0.w);
            v[4] = fmaf(dr, a[4], bia1.x); v[5] = fmaf(dr, a[5], bia1.y);
            v[6] = fmaf(dr, a[6], bia1.z); v[7] = fmaf(dr, a[7], bia1.w);
            if (RELU) {
#pragma unroll
                for (int t = 0; t < 8; ++t) v[t] = fmaxf(v[t], 0.f);
            }
            float* op = OUT + (size_t)r * DD + c * 8;
            *(float4*)op       = make_float4(v[0], v[1], v[2], v[3]);
            *(float4*)(op + 4) = make_float4(v[4], v[5], v[6], v[7]);
#pragma unroll
            for (int t = 0; t < 8; ++t) { sum[t] += v[t]; sq[t] += v[t] * v[t]; }
        }
    }

    __shared__ float redS[4][16][8];
    __shared__ float redQ[4][16][8];
    if (jj == 0) {
#pragma unroll
        for (int t = 0; t < 8; ++t) { redS[wid][c][t] = sum[t]; redQ[wid][c][t] = sq[t]; }
    }
    __syncthreads();
    if (tid < 128) {
        int ci = tid >> 3, ct = tid & 7;
        float S = (redS[0][ci][ct] + redS[1][ci][ct]) + (redS[2][ci][ct] + redS[3][ci][ct]);
        float Q = (redQ[0][ci][ct] + redQ[1][ci][ct]) + (redQ[2][ci][ct] + redQ[3][ci][ct]);
        atomicAdd(&colsum[tid], S);
        atomicAdd(&colsumsq[tid], Q);
    }
}

extern "C" void kernel_launch(void* const* d_in, const int* in_sizes, int n_in,
                              void* d_out, int out_size, void* d_ws, size_t ws_size,
                              hipStream_t stream) {
    const float* x      = (const float*)d_in[0];
    const int*   ei     = (const int*)d_in[1];
    const float* conv_w = (const float*)d_in[2];
    const float* conv_b = (const float*)d_in[3];
    const float* bn_g   = (const float*)d_in[4];
    const float* bn_b   = (const float*)d_in[5];
    const float* mlp_w  = (const float*)d_in[6];
    const float* mlp_b  = (const float*)d_in[7];
    const float* out_w  = (const float*)d_in[8];
    const float* out_b  = (const float*)d_in[9];
    float* out = (float*)d_out;

    const size_t ND4 = (size_t)NN * DD * 4;   // 25,600,000 B
    char* ws = (char*)d_ws;
    size_t off = 0;
    float* B0      = (float*)(ws + off); off += ND4;                // fp32 features
    unsigned short* B1b = (unsigned short*)(ws + off); off += ND4 / 2 + 256;  // bf16 HS + pad row NN
    int*   deg     = (int*)  (ws + off); off += 204800;             // zeroed region start
    float* cs3     = (float*)(ws + off); off += 3 * 512;
    float* css3    = (float*)(ws + off); off += 3 * 512;            // zeroed region end
    float* dis     = (float*)(ws + off); off += 204800;
    int*   rowptr  = (int*)  (ws + off); off += 204804 + 60;
    int*   cursor  = (int*)  (ws + off); off += 204800;
    int*   bsum    = (int*)  (ws + off); off += 1024;
    unsigned short* Wfb = (unsigned short*)(ws + off); off += 5 * 16384 * 2;
    int*   csr     = (int*)  (ws + off); off += (size_t)EE * 4;
    int*   ell     = (int*)  (ws + off); off += (size_t)NN * 32 * 4;  // 6.4MB
    // total ≈ 49.2 MB

    const int gemm_grid = (NN + 63) / 64;     // 782
    const int nscan = (NN + 255) / 256;       // 196
    const int gather_grid = 2048;             // 8192 waves

    hipMemsetAsync(deg, 0, 204800 + 6 * 512, stream);

    k_deg<<<(EE + 255) / 256, 256, 0, stream>>>(ei, deg);
    k_scan_block<<<nscan, 256, 0, stream>>>(deg, cursor, bsum);
    k_scan_final<<<nscan, 256, 0, stream>>>(deg, cursor, bsum, nscan, rowptr, cursor, dis);
    k_fill<<<(EE + 255) / 256, 256, 0, stream>>>(ei, cursor, csr);
    k_ell<<<(NN * 32 + 255) / 256, 256, 0, stream>>>(rowptr, csr, ell);
    k_wprep<<<321, 256, 0, stream>>>(conv_w, mlp_w, Wfb, (unsigned int*)(B1b + (size_t)NN * DD));

    // ---- layer 0 ----
    k_gemm_conv<0><<<gemm_grid, 256, 0, stream>>>(x, Wfb, dis,
        nullptr, nullptr, nullptr, nullptr, B1b);
    k_gather<0><<<gather_grid, 256, 0, stream>>>(rowptr, csr, ell, (const uint4*)B1b, dis, conv_b, B0, cs3, css3);

    // ---- layer 1 ----
    k_gemm_conv<1><<<gemm_grid, 256, 0, stream>>>(B0, Wfb + 16384, dis,
        cs3, css3, bn_g, bn_b, B1b);
    k_gather<0><<<gather_grid, 256, 0, stream>>>(rowptr, csr, ell, (const uint4*)B1b, dis, conv_b + DD, B0, cs3 + 128, css3 + 128);

    // ---- layer 2 ----
    k_gemm_conv<1><<<gemm_grid, 256, 0, stream>>>(B0, Wfb + 2 * 16384, dis,
        cs3 + 128, css3 + 128, bn_g + DD, bn_b + DD, B1b);
    k_gather<1><<<gather_grid, 256, 0, stream>>>(rowptr, csr, ell, (const uint4*)B1b, dis, conv_b + 2 * DD, B0, cs3 + 256, css3 + 256);

    // ---- fused MLP + head ----
    k_mlp_head<<<gemm_grid, 256, 0, stream>>>(B0, Wfb + 3 * 16384, Wfb + 4 * 16384,
        mlp_b, mlp_b + DD, cs3 + 256, css3 + 256, bn_g + DD, bn_b + DD, out_w, out_b, out);
}